// Round 11
// baseline (213.557 us; speedup 1.0000x reference)
//
#include <hip/hip_runtime.h>
#include <hip/hip_cooperative_groups.h>
#include <cmath>

namespace cg = cooperative_groups;

// Problem constants (fixed by setup_inputs)
#define BB 32
#define EE 256
#define NC 1024
#define NF 4096
#define TOKSTRIDE 5120   // Nc+Nf rows per batch
#define IMG 256
#define MAXHF 64

typedef _Float16 f16x8 __attribute__((ext_vector_type(8)));
typedef _Float16 f16x4 __attribute__((ext_vector_type(4)));
typedef float    f32x4 __attribute__((ext_vector_type(4)));

struct SampArgs {
    int i0[32]; int i1[32]; float fr[32];
    int hfl[MAXHF];   // needed hf values (sorted), nhf entries
    int inv[64];      // hf -> dense index in hfl
    int nhf, nj, jblocks;
};

// ---------------- device pieces (shared by mega-kernel and fallback) ----------------

__device__ __forceinline__ void dev_scan(int b, const int* mask, int* cum,
                                         int tid, int* sums) {
    const int* m = mask + b * NF;
    int loc[16];
    int s = 0;
    #pragma unroll
    for (int i = 0; i < 16; ++i) { int v = (m[tid*16 + i] != 0) ? 1 : 0; s += v; loc[i] = s; }
    sums[tid] = s;
    __syncthreads();
    for (int off = 1; off < 256; off <<= 1) {
        int v = sums[tid];
        int add = (tid >= off) ? sums[tid - off] : 0;
        __syncthreads();
        sums[tid] = v + add;
        __syncthreads();
    }
    int excl = sums[tid] - s;
    #pragma unroll
    for (int i = 0; i < 16; ++i) cum[b*NF + tid*16 + i] = excl + loc[i];
}

__device__ __forceinline__ void dev_coarse(int t, const float* tokens,
                                           const float* Wc, const float* bc,
                                           _Float16* coarse_img,
                                           int tid, char* xbase) {
    const int b  = t >> 4;
    const int t0 = (t & 15) * 64;
    const int lane = tid & 63;
    const int wave = tid >> 6;
    const int colg = lane & 15;
    const int kg   = lane >> 4;

    const float* src = tokens + ((size_t)b * TOKSTRIDE + t0) * EE;
    #pragma unroll
    for (int i = 0; i < 8; ++i) {
        int pp  = i * 256 + tid;
        int row = pp >> 5;
        int cp  = pp & 31;
        const float* s = src + (size_t)row * EE + cp * 8;
        float4 v0 = *reinterpret_cast<const float4*>(s);
        float4 v1 = *reinterpret_cast<const float4*>(s + 4);
        f16x8 h;
        h[0] = (_Float16)v0.x; h[1] = (_Float16)v0.y;
        h[2] = (_Float16)v0.z; h[3] = (_Float16)v0.w;
        h[4] = (_Float16)v1.x; h[5] = (_Float16)v1.y;
        h[6] = (_Float16)v1.z; h[7] = (_Float16)v1.w;
        *reinterpret_cast<f16x8*>(xbase + row * 512 + ((cp ^ (row & 7)) << 4)) = h;
    }

    const int c0 = wave * 16;
    f16x8 bfrag[8];
    #pragma unroll
    for (int kt = 0; kt < 8; ++kt) {
        #pragma unroll
        for (int j = 0; j < 8; ++j) {
            int k = kt * 32 + kg * 8 + j;
            bfrag[kt][j] = (_Float16)Wc[k * 64 + c0 + colg];
        }
    }
    __syncthreads();

    f32x4 acc[4];
    #pragma unroll
    for (int mt = 0; mt < 4; ++mt) acc[mt] = (f32x4){0.f, 0.f, 0.f, 0.f};

    #pragma unroll
    for (int kt = 0; kt < 8; ++kt) {
        #pragma unroll
        for (int mt = 0; mt < 4; ++mt) {
            const int arow = mt * 16 + colg;
            const int chunk = kt * 4 + kg;
            f16x8 a = *reinterpret_cast<const f16x8*>(
                xbase + arow * 512 + ((chunk ^ (arow & 7)) << 4));
            acc[mt] = __builtin_amdgcn_mfma_f32_16x16x32_f16(a, bfrag[kt], acc[mt], 0, 0, 0);
        }
    }

    const int col  = c0 + colg;
    const float bias = bc[col];
    const int ph = col >> 3, pw = col & 7;
    #pragma unroll
    for (int mt = 0; mt < 4; ++mt) {
        #pragma unroll
        for (int r = 0; r < 4; ++r) {
            int tg = t0 + mt * 16 + kg * 4 + r;
            int hc = tg >> 5, wc = tg & 31;
            coarse_img[(size_t)b * 65536 + (hc * 8 + ph) * 256 + wc * 8 + pw]
                = (_Float16)(acc[mt][r] + bias);
        }
    }
}

__device__ __forceinline__ void dev_fine(int u0blk, const float* tokens,
                                         const float* Wf, const float* bf,
                                         const int* mask, const int* cum,
                                         _Float16* patch_j, const SampArgs& sa,
                                         int tid, char* xbase, int* rowsrc) {
    const int b  = u0blk / sa.jblocks;
    const int u0 = (u0blk - b * sa.jblocks) * 64;
    const int lane = tid & 63;
    const int wave = tid >> 6;
    const int colg = lane & 15;
    const int kg   = lane >> 4;

    if (tid < 64) {
        int u = u0 + tid;
        int ridx = -1;
        if (u < sa.nj) {
            int uh = u / sa.nhf;
            int uw = u - uh * sa.nhf;
            int j  = sa.hfl[uh] * 64 + sa.hfl[uw];
            if (mask[b * NF + j] != 0) ridx = cum[b * NF + j] - 1;
        }
        rowsrc[tid] = ridx;
    }
    __syncthreads();

    const int rgrp   = tid >> 6;
    const int lane64 = tid & 63;
    for (int it = 0; it < 16; ++it) {
        int rl = it * 4 + rgrp;
        int ridx = rowsrc[rl];
        int cp   = lane64 >> 1;
        int half = lane64 & 1;
        f16x4 hv = {0, 0, 0, 0};
        if (ridx >= 0) {
            const float* s = tokens + ((size_t)b * TOKSTRIDE + NC + ridx) * EE + lane64 * 4;
            float4 v = *reinterpret_cast<const float4*>(s);
            hv[0] = (_Float16)v.x; hv[1] = (_Float16)v.y;
            hv[2] = (_Float16)v.z; hv[3] = (_Float16)v.w;
        }
        *reinterpret_cast<f16x4*>(xbase + rl * 512 + (((cp ^ (rl & 7)) << 4) | (half << 3))) = hv;
    }

    f16x8 bfrag[8];
    #pragma unroll
    for (int kt = 0; kt < 8; ++kt) {
        #pragma unroll
        for (int j = 0; j < 8; ++j) {
            int k = kt * 32 + kg * 8 + j;
            bfrag[kt][j] = (_Float16)Wf[k * 16 + colg];
        }
    }
    __syncthreads();

    const int arow = wave * 16 + colg;
    const char* xrow = xbase + arow * 512;
    const int swz = arow & 7;
    f32x4 acc = {0.f, 0.f, 0.f, 0.f};
    #pragma unroll
    for (int kt = 0; kt < 8; ++kt) {
        const int chunk = kt * 4 + kg;
        f16x8 a = *reinterpret_cast<const f16x8*>(xrow + ((chunk ^ swz) << 4));
        acc = __builtin_amdgcn_mfma_f32_16x16x32_f16(a, bfrag[kt], acc, 0, 0, 0);
    }

    const float bias = bf[colg];
    #pragma unroll
    for (int r = 0; r < 4; ++r) {
        int ol = wave * 16 + kg * 4 + r;
        int u  = u0 + ol;
        if (u < sa.nj) {
            float v = (rowsrc[ol] >= 0) ? (acc[r] + bias) : 0.f;
            patch_j[((size_t)b * sa.nj + u) * 16 + colg] = (_Float16)v;
        }
    }
}

__device__ __forceinline__ void dev_out(int t, const _Float16* coarse_img,
                                        const _Float16* patch_j,
                                        const float* noise, const float* convw,
                                        float* out, const SampArgs& sa, int tid) {
    const int gt = t * 256 + tid;
    const int o  = gt >> 2;
    const int corner = gt & 3;
    const int a = corner >> 1, c = corner & 1;

    const int b = o >> 10;
    const int p = (o >> 5) & 31;
    const int q = o & 31;

    float kk[9];
    #pragma unroll
    for (int i = 0; i < 9; ++i) kk[i] = convw[i];

    const int   h  = a ? sa.i1[p] : sa.i0[p];
    const int   w  = c ? sa.i1[q] : sa.i0[q];
    const float fh = sa.fr[p], fw = sa.fr[q];
    const float wt = (a ? fh : 1.f - fh) * (c ? fw : 1.f - fw);

    const _Float16* cimg = coarse_img + (size_t)b*65536;
    const float*    nimg = noise      + (size_t)b*65536;

    float conv = 0.f;
    #pragma unroll
    for (int dh = -1; dh <= 1; ++dh) {
        #pragma unroll
        for (int dw = -1; dw <= 1; ++dw) {
            int hh = h + dh, wp = w + dw;
            float v = (hh >= 0 && hh < IMG && wp >= 0 && wp < IMG)
                      ? (float)cimg[hh*IMG + wp] : 0.f;
            conv = fmaf(v, kk[(dh+1)*3 + (dw+1)], conv);
        }
    }
    const int jj = sa.inv[h >> 2] * sa.nhf + sa.inv[w >> 2];
    const int colx = (h & 3) * 4 + (w & 3);
    float fv = (float)patch_j[((size_t)b * sa.nj + jj) * 16 + colx];

    float s = 1.f / (1.f + expf(-0.1f * nimg[h*IMG + w]));
    float val = wt * (conv * (1.f - s) + fv * s);

    val += __shfl_xor(val, 1, 64);
    val += __shfl_xor(val, 2, 64);
    if (corner == 0) out[o] = val;
}

// ---------------- mega-kernel: scan | mm | out with grid sync ----------------
__global__ __launch_bounds__(256, 4) void k_all(const float* tokens,
                                                const int* mask,
                                                const float* Wc, const float* bc,
                                                const float* Wf, const float* bf,
                                                const float* convw, const float* noise,
                                                float* out,
                                                _Float16* coarse_img,
                                                _Float16* patch_j,
                                                int* cum,
                                                SampArgs sa, int G, int tilesB) {
    __shared__ char xmem[64 * 512];     // 32 KB
    __shared__ int  aux[256];
    cg::grid_group grid = cg::this_grid();
    const int tid = threadIdx.x;

    for (int t = blockIdx.x; t < BB; t += G) {
        __syncthreads();
        dev_scan(t, mask, cum, tid, aux);
    }
    grid.sync();

    for (int t = blockIdx.x; t < tilesB; t += G) {
        __syncthreads();
        if (t < 512) dev_coarse(t, tokens, Wc, bc, coarse_img, tid, xmem);
        else         dev_fine(t - 512, tokens, Wf, bf, mask, cum, patch_j, sa, tid, xmem, aux);
    }
    grid.sync();

    for (int t = blockIdx.x; t < 512; t += G)
        dev_out(t, coarse_img, patch_j, noise, convw, out, sa, tid);
}

// ---------------- fallback kernels (3-launch path) ----------------
__global__ __launch_bounds__(256) void k_scan_f(const int* mask, int* cum) {
    __shared__ int sums[256];
    dev_scan(blockIdx.x, mask, cum, threadIdx.x, sums);
}

__global__ __launch_bounds__(256, 4) void k_mm_f(const float* tokens,
                                                 const float* Wc, const float* bc,
                                                 const float* Wf, const float* bf,
                                                 const int* mask, const int* cum,
                                                 _Float16* coarse_img,
                                                 _Float16* patch_j, SampArgs sa) {
    __shared__ char xmem[64 * 512];
    __shared__ int  aux[256];
    if (blockIdx.x < 512) dev_coarse(blockIdx.x, tokens, Wc, bc, coarse_img, threadIdx.x, xmem);
    else                  dev_fine(blockIdx.x - 512, tokens, Wf, bf, mask, cum, patch_j, sa,
                                   threadIdx.x, xmem, aux);
}

__global__ __launch_bounds__(256) void k_out_f(const _Float16* coarse_img,
                                               const _Float16* patch_j,
                                               const float* noise, const float* convw,
                                               float* out, SampArgs sa) {
    dev_out(blockIdx.x, coarse_img, patch_j, noise, convw, out, sa, threadIdx.x);
}

extern "C" void kernel_launch(void* const* d_in, const int* in_sizes, int n_in,
                              void* d_out, int out_size, void* d_ws, size_t ws_size,
                              hipStream_t stream) {
    const float* tokens = (const float*)d_in[0];
    const int*   mask   = (const int*)  d_in[1];
    const float* Wc     = (const float*)d_in[2];
    const float* bc     = (const float*)d_in[3];
    const float* Wf     = (const float*)d_in[4];
    const float* bf     = (const float*)d_in[5];
    const float* convw  = (const float*)d_in[6];
    const float* noise  = (const float*)d_in[7];
    float* outp = (float*)d_out;

    // interp + needed-hf structures (host, deterministic)
    SampArgs sa;
    bool need[64] = {false};
    for (int p = 0; p < 32; ++p) {
        double pos = (double)p * 255.0 / 31.0;
        int i0 = (int)floor(pos);
        int i1 = (i0 + 1 < 256) ? i0 + 1 : 255;
        sa.i0[p] = i0; sa.i1[p] = i1; sa.fr[p] = (float)(pos - (double)i0);
        need[i0 >> 2] = true; need[i1 >> 2] = true;
    }
    int nhf = 0;
    for (int hf = 0; hf < 64; ++hf) {
        sa.inv[hf] = 0;
        if (need[hf]) { sa.inv[hf] = nhf; sa.hfl[nhf++] = hf; }
    }
    for (int i = nhf; i < MAXHF; ++i) sa.hfl[i] = 0;
    sa.nhf = nhf;
    sa.nj  = nhf * nhf;
    sa.jblocks = (sa.nj + 63) / 64;

    char* wsb = (char*)d_ws;
    _Float16* coarse_img = (_Float16*)wsb;                                   // 4.19 MB
    _Float16* patch_j    = (_Float16*)(wsb + (size_t)BB*65536*2);            // <=4.19 MB
    int*      cum        = (int*)(wsb + (size_t)BB*65536*2 + (size_t)BB*NF*16*2);

    const int tilesB = 512 + BB * sa.jblocks;

    int occ = 0;
    hipError_t oe = hipOccupancyMaxActiveBlocksPerMultiprocessor(&occ, (const void*)k_all, 256, 0);
    int G = (oe == hipSuccess && occ > 0) ? occ * 256 : 0;
    if (G > tilesB) G = tilesB;

    bool done = false;
    if (G > 0) {
        void* args[] = { (void*)&tokens, (void*)&mask, (void*)&Wc, (void*)&bc,
                         (void*)&Wf, (void*)&bf, (void*)&convw, (void*)&noise,
                         (void*)&outp, (void*)&coarse_img, (void*)&patch_j,
                         (void*)&cum, (void*)&sa, (void*)&G, (void*)&tilesB };
        hipError_t e = hipLaunchCooperativeKernel((void*)k_all, dim3(G), dim3(256),
                                                  args, 0, stream);
        done = (e == hipSuccess);
    }
    if (!done) {
        k_scan_f<<<32,     256, 0, stream>>>(mask, cum);
        k_mm_f  <<<tilesB, 256, 0, stream>>>(tokens, Wc, bc, Wf, bf, mask, cum,
                                             coarse_img, patch_j, sa);
        k_out_f <<<512,    256, 0, stream>>>(coarse_img, patch_j, noise, convw, outp, sa);
    }
}

// Round 12
// 32.491 us; speedup vs baseline: 6.5727x; 6.5727x over previous
//
#include <hip/hip_runtime.h>
#include <cmath>

// Problem constants (fixed by setup_inputs)
#define BB 32
#define EE 256
#define NC 1024
#define NF 4096
#define TOKSTRIDE 5120   // Nc+Nf rows per batch
#define IMG 256
#define MAXHF 64

typedef _Float16 f16x8 __attribute__((ext_vector_type(8)));
typedef _Float16 f16x4 __attribute__((ext_vector_type(4)));
typedef float    f32x4 __attribute__((ext_vector_type(4)));

struct SampArgs {
    int i0[32]; int i1[32]; float fr[32];
    int hfl[MAXHF];   // needed hf values (sorted), nhf entries
    int inv[64];      // hf -> dense index in hfl
    int nhf, nj, jblocks;
};

// ---------------- K0: scan (32 blocks) + W-fragment precompute (2 blocks) ----------------
__global__ __launch_bounds__(256) void k_pre(const int* __restrict__ mask,
                                             int* __restrict__ cum,
                                             const float* __restrict__ Wc,
                                             const float* __restrict__ Wf,
                                             f16x8* __restrict__ wc_frag,
                                             f16x8* __restrict__ wf_frag) {
    __shared__ int sums[256];
    const int tid = threadIdx.x;

    if (blockIdx.x < 32) {
        const int b = blockIdx.x;
        const int* m = mask + b * NF;
        int loc[16];
        int s = 0;
        #pragma unroll
        for (int i = 0; i < 16; ++i) { int v = (m[tid*16 + i] != 0) ? 1 : 0; s += v; loc[i] = s; }
        sums[tid] = s;
        __syncthreads();
        for (int off = 1; off < 256; off <<= 1) {
            int v = sums[tid];
            int add = (tid >= off) ? sums[tid - off] : 0;
            __syncthreads();
            sums[tid] = v + add;
            __syncthreads();
        }
        int excl = sums[tid] - s;
        #pragma unroll
        for (int i = 0; i < 16; ++i) cum[b*NF + tid*16 + i] = excl + loc[i];
    } else if (blockIdx.x == 32) {
        // coarse fragments: wc_frag[tid*8 + kt]
        const int lane = tid & 63;
        const int wave = tid >> 6;
        const int colg = lane & 15;
        const int kg   = lane >> 4;
        const int c0   = wave * 16;
        #pragma unroll
        for (int kt = 0; kt < 8; ++kt) {
            f16x8 h;
            #pragma unroll
            for (int j = 0; j < 8; ++j)
                h[j] = (_Float16)Wc[(kt * 32 + kg * 8 + j) * 64 + c0 + colg];
            wc_frag[tid * 8 + kt] = h;
        }
    } else {
        // fine fragments: wf_frag[lane*8 + kt]
        if (tid < 64) {
            const int colg = tid & 15;
            const int kg   = tid >> 4;
            #pragma unroll
            for (int kt = 0; kt < 8; ++kt) {
                f16x8 h;
                #pragma unroll
                for (int j = 0; j < 8; ++j)
                    h[j] = (_Float16)Wf[(kt * 32 + kg * 8 + j) * 16 + colg];
                wf_frag[tid * 8 + kt] = h;
            }
        }
    }
}

// ---------------- K13: fused coarse GEMM + sparse fine gather-GEMM ----------------
__global__ __launch_bounds__(256) void k_mm(const float* __restrict__ tokens,
                                            const float* __restrict__ bc,
                                            const float* __restrict__ bf,
                                            const int* __restrict__ mask,
                                            const int* __restrict__ cum,
                                            const f16x8* __restrict__ wc_frag,
                                            const f16x8* __restrict__ wf_frag,
                                            _Float16* __restrict__ coarse_img,
                                            _Float16* __restrict__ patch_j,
                                            SampArgs sa) {
    __shared__ _Float16 Xs[64 * 256];          // 32 KB
    __shared__ int rowsrc[64];
    const int tid  = threadIdx.x;
    const int lane = tid & 63;
    const int wave = tid >> 6;
    char* xbase = reinterpret_cast<char*>(Xs);
    const int colg = lane & 15;
    const int kg   = lane >> 4;

    if (blockIdx.x < 512) {
        // ---- coarse role: dense 64-token tile ----
        const int b  = blockIdx.x >> 4;
        const int t0 = (blockIdx.x & 15) * 64;

        // fragment loads first (128 B/thread, coalesced) -- in flight under staging
        f16x8 bfrag[8];
        const f16x8* wsrc = wc_frag + tid * 8;
        #pragma unroll
        for (int kt = 0; kt < 8; ++kt) bfrag[kt] = wsrc[kt];

        const float* src = tokens + ((size_t)b * TOKSTRIDE + t0) * EE;
        #pragma unroll
        for (int i = 0; i < 8; ++i) {
            int pp  = i * 256 + tid;
            int row = pp >> 5;
            int cp  = pp & 31;
            const float* s = src + (size_t)row * EE + cp * 8;
            float4 v0 = *reinterpret_cast<const float4*>(s);
            float4 v1 = *reinterpret_cast<const float4*>(s + 4);
            f16x8 h;
            h[0] = (_Float16)v0.x; h[1] = (_Float16)v0.y;
            h[2] = (_Float16)v0.z; h[3] = (_Float16)v0.w;
            h[4] = (_Float16)v1.x; h[5] = (_Float16)v1.y;
            h[6] = (_Float16)v1.z; h[7] = (_Float16)v1.w;
            *reinterpret_cast<f16x8*>(xbase + row * 512 + ((cp ^ (row & 7)) << 4)) = h;
        }
        __syncthreads();

        f32x4 acc[4];
        #pragma unroll
        for (int mt = 0; mt < 4; ++mt) acc[mt] = (f32x4){0.f, 0.f, 0.f, 0.f};

        #pragma unroll
        for (int kt = 0; kt < 8; ++kt) {
            #pragma unroll
            for (int mt = 0; mt < 4; ++mt) {
                const int arow = mt * 16 + colg;
                const int chunk = kt * 4 + kg;
                f16x8 a = *reinterpret_cast<const f16x8*>(
                    xbase + arow * 512 + ((chunk ^ (arow & 7)) << 4));
                acc[mt] = __builtin_amdgcn_mfma_f32_16x16x32_f16(a, bfrag[kt], acc[mt], 0, 0, 0);
            }
        }

        const int col  = wave * 16 + colg;
        const float bias = bc[col];
        const int ph = col >> 3, pw = col & 7;
        #pragma unroll
        for (int mt = 0; mt < 4; ++mt) {
            #pragma unroll
            for (int r = 0; r < 4; ++r) {
                int tg = t0 + mt * 16 + kg * 4 + r;
                int hc = tg >> 5, wc = tg & 31;
                coarse_img[(size_t)b * 65536 + (hc * 8 + ph) * 256 + wc * 8 + pw]
                    = (_Float16)(acc[mt][r] + bias);
            }
        }
    } else {
        // ---- fine role: 64 needed-j's, gathered rows ----
        const int u0blk = blockIdx.x - 512;
        const int b  = u0blk / sa.jblocks;
        const int u0 = (u0blk - b * sa.jblocks) * 64;

        f16x8 bfrag[8];
        const f16x8* wsrc = wf_frag + lane * 8;
        #pragma unroll
        for (int kt = 0; kt < 8; ++kt) bfrag[kt] = wsrc[kt];

        if (tid < 64) {
            int u = u0 + tid;
            int ridx = -1;
            if (u < sa.nj) {
                int uh = u / sa.nhf;
                int uw = u - uh * sa.nhf;
                int j  = sa.hfl[uh] * 64 + sa.hfl[uw];
                if (mask[b * NF + j] != 0) ridx = cum[b * NF + j] - 1;
            }
            rowsrc[tid] = ridx;
        }
        __syncthreads();

        const int rgrp   = tid >> 6;
        const int lane64 = tid & 63;
        for (int it = 0; it < 16; ++it) {
            int rl = it * 4 + rgrp;
            int ridx = rowsrc[rl];
            int cp   = lane64 >> 1;
            int half = lane64 & 1;
            f16x4 hv = {0, 0, 0, 0};
            if (ridx >= 0) {
                const float* s = tokens + ((size_t)b * TOKSTRIDE + NC + ridx) * EE + lane64 * 4;
                float4 v = *reinterpret_cast<const float4*>(s);
                hv[0] = (_Float16)v.x; hv[1] = (_Float16)v.y;
                hv[2] = (_Float16)v.z; hv[3] = (_Float16)v.w;
            }
            *reinterpret_cast<f16x4*>(xbase + rl * 512 + (((cp ^ (rl & 7)) << 4) | (half << 3))) = hv;
        }
        __syncthreads();

        const int arow = wave * 16 + colg;
        const char* xrow = xbase + arow * 512;
        const int swz = arow & 7;
        f32x4 acc = {0.f, 0.f, 0.f, 0.f};
        #pragma unroll
        for (int kt = 0; kt < 8; ++kt) {
            const int chunk = kt * 4 + kg;
            f16x8 a = *reinterpret_cast<const f16x8*>(xrow + ((chunk ^ swz) << 4));
            acc = __builtin_amdgcn_mfma_f32_16x16x32_f16(a, bfrag[kt], acc, 0, 0, 0);
        }

        const float bias = bf[colg];
        #pragma unroll
        for (int r = 0; r < 4; ++r) {
            int ol = wave * 16 + kg * 4 + r;
            int u  = u0 + ol;
            if (u < sa.nj) {
                float v = (rowsrc[ol] >= 0) ? (acc[r] + bias) : 0.f;
                patch_j[((size_t)b * sa.nj + u) * 16 + colg] = (_Float16)v;
            }
        }
    }
}

// ---------------- K4: fused conv + blend + downsample (4 lanes/pixel) ----------------
__global__ __launch_bounds__(256) void k_out(const _Float16* __restrict__ coarse_img,
                                             const _Float16* __restrict__ patch_j,
                                             const float* __restrict__ noise,
                                             const float* __restrict__ convw,
                                             float* __restrict__ out,
                                             SampArgs sa) {
    const int gt = blockIdx.x * 256 + threadIdx.x;    // 131072 threads
    const int o  = gt >> 2;                           // output index 0..32767
    const int corner = gt & 3;
    const int a = corner >> 1, c = corner & 1;

    const int b = o >> 10;
    const int p = (o >> 5) & 31;
    const int q = o & 31;

    float kk[9];
    #pragma unroll
    for (int i = 0; i < 9; ++i) kk[i] = convw[i];

    const int   h  = a ? sa.i1[p] : sa.i0[p];
    const int   w  = c ? sa.i1[q] : sa.i0[q];
    const float fh = sa.fr[p], fw = sa.fr[q];
    const float wt = (a ? fh : 1.f - fh) * (c ? fw : 1.f - fw);

    const _Float16* cimg = coarse_img + (size_t)b*65536;
    const float*    nimg = noise      + (size_t)b*65536;

    float conv = 0.f;
    #pragma unroll
    for (int dh = -1; dh <= 1; ++dh) {
        #pragma unroll
        for (int dw = -1; dw <= 1; ++dw) {
            int hh = h + dh, wp = w + dw;
            float v = (hh >= 0 && hh < IMG && wp >= 0 && wp < IMG)
                      ? (float)cimg[hh*IMG + wp] : 0.f;
            conv = fmaf(v, kk[(dh+1)*3 + (dw+1)], conv);
        }
    }
    const int jj = sa.inv[h >> 2] * sa.nhf + sa.inv[w >> 2];
    const int colx = (h & 3) * 4 + (w & 3);
    float fv = (float)patch_j[((size_t)b * sa.nj + jj) * 16 + colx];

    float s = 1.f / (1.f + expf(-0.1f * nimg[h*IMG + w]));
    float val = wt * (conv * (1.f - s) + fv * s);

    val += __shfl_xor(val, 1, 64);
    val += __shfl_xor(val, 2, 64);
    if (corner == 0) out[o] = val;
}

extern "C" void kernel_launch(void* const* d_in, const int* in_sizes, int n_in,
                              void* d_out, int out_size, void* d_ws, size_t ws_size,
                              hipStream_t stream) {
    const float* tokens = (const float*)d_in[0];
    const int*   mask   = (const int*)  d_in[1];
    const float* Wc     = (const float*)d_in[2];
    const float* bc     = (const float*)d_in[3];
    const float* Wf     = (const float*)d_in[4];
    const float* bf     = (const float*)d_in[5];
    const float* convw  = (const float*)d_in[6];
    const float* noise  = (const float*)d_in[7];

    // interp + needed-hf structures (host, deterministic)
    SampArgs sa;
    bool need[64] = {false};
    for (int p = 0; p < 32; ++p) {
        double pos = (double)p * 255.0 / 31.0;
        int i0 = (int)floor(pos);
        int i1 = (i0 + 1 < 256) ? i0 + 1 : 255;
        sa.i0[p] = i0; sa.i1[p] = i1; sa.fr[p] = (float)(pos - (double)i0);
        need[i0 >> 2] = true; need[i1 >> 2] = true;
    }
    int nhf = 0;
    for (int hf = 0; hf < 64; ++hf) {
        sa.inv[hf] = 0;
        if (need[hf]) { sa.inv[hf] = nhf; sa.hfl[nhf++] = hf; }
    }
    for (int i = nhf; i < MAXHF; ++i) sa.hfl[i] = 0;
    sa.nhf = nhf;
    sa.nj  = nhf * nhf;
    sa.jblocks = (sa.nj + 63) / 64;

    char* wsb = (char*)d_ws;
    _Float16* coarse_img = (_Float16*)wsb;                          // 4,194,304 B
    _Float16* patch_j    = (_Float16*)(wsb + 4194304);              // 4,194,304 B (cap)
    int*      cum        = (int*)(wsb + 8388608);                   //   524,288 B
    f16x8*    wc_frag    = (f16x8*)(wsb + 8912896);                 //    32,768 B
    f16x8*    wf_frag    = (f16x8*)(wsb + 8945664);                 //     8,192 B

    const int tilesB = 512 + BB * sa.jblocks;

    k_pre<<<34, 256, 0, stream>>>(mask, cum, Wc, Wf, wc_frag, wf_frag);
    k_mm <<<tilesB, 256, 0, stream>>>(tokens, bc, bf, mask, cum, wc_frag, wf_frag,
                                      coarse_img, patch_j, sa);
    k_out<<<512, 256, 0, stream>>>(coarse_img, patch_j, noise, convw,
                                   (float*)d_out, sa);
}

// Round 13
// 26.391 us; speedup vs baseline: 8.0919x; 1.2311x over previous
//
#include <hip/hip_runtime.h>
#include <cmath>

// Problem constants (fixed by setup_inputs)
#define BB 32
#define EE 256
#define NC 1024
#define NF 4096
#define TOKSTRIDE 5120   // Nc+Nf rows per batch
#define IMG 256
#define MAXHF 64

typedef _Float16 f16x8 __attribute__((ext_vector_type(8)));
typedef _Float16 f16x4 __attribute__((ext_vector_type(4)));
typedef float    f32x4 __attribute__((ext_vector_type(4)));

struct SampArgs {
    int i0[32]; int i1[32]; float fr[32];
    int hfl[MAXHF];   // needed hf values (sorted), nhf entries
    int inv[64];      // hf -> dense index in hfl
    int nhf, nj, jblocks;
};

// ---------------- K1: coarse GEMM (blocks 0..511) + mask scan (blocks 512..543) ----------------
// Coarse and scan are independent; fusing hides the scan's serial latency
// under the coarse GEMM and removes one kernel-boundary drain.
__global__ __launch_bounds__(256) void k_mm1(const float* __restrict__ tokens,
                                             const float* __restrict__ Wc,
                                             const float* __restrict__ bc,
                                             const int* __restrict__ mask,
                                             int* __restrict__ cum,
                                             float* __restrict__ coarse_img) {
    __shared__ _Float16 Xs[64 * 256];          // 32 KB (scan aliases as int*)
    const int tid  = threadIdx.x;

    if (blockIdx.x >= 512) {
        // ---- scan role ----
        int* sums = reinterpret_cast<int*>(Xs);
        const int b = blockIdx.x - 512;
        const int* m = mask + b * NF;
        int loc[16];
        int s = 0;
        #pragma unroll
        for (int i = 0; i < 16; ++i) { int v = (m[tid*16 + i] != 0) ? 1 : 0; s += v; loc[i] = s; }
        sums[tid] = s;
        __syncthreads();
        for (int off = 1; off < 256; off <<= 1) {
            int v = sums[tid];
            int add = (tid >= off) ? sums[tid - off] : 0;
            __syncthreads();
            sums[tid] = v + add;
            __syncthreads();
        }
        int excl = sums[tid] - s;
        #pragma unroll
        for (int i = 0; i < 16; ++i) cum[b*NF + tid*16 + i] = excl + loc[i];
        return;
    }

    // ---- coarse role: dense 64-token tile ----
    const int lane = tid & 63;
    const int wave = tid >> 6;
    char* xbase = reinterpret_cast<char*>(Xs);
    const int colg = lane & 15;
    const int kg   = lane >> 4;

    const int b  = blockIdx.x >> 4;
    const int t0 = (blockIdx.x & 15) * 64;

    const float* src = tokens + ((size_t)b * TOKSTRIDE + t0) * EE;
    #pragma unroll
    for (int i = 0; i < 8; ++i) {
        int pp  = i * 256 + tid;
        int row = pp >> 5;
        int cp  = pp & 31;
        const float* s = src + (size_t)row * EE + cp * 8;
        float4 v0 = *reinterpret_cast<const float4*>(s);
        float4 v1 = *reinterpret_cast<const float4*>(s + 4);
        f16x8 h;
        h[0] = (_Float16)v0.x; h[1] = (_Float16)v0.y;
        h[2] = (_Float16)v0.z; h[3] = (_Float16)v0.w;
        h[4] = (_Float16)v1.x; h[5] = (_Float16)v1.y;
        h[6] = (_Float16)v1.z; h[7] = (_Float16)v1.w;
        *reinterpret_cast<f16x8*>(xbase + row * 512 + ((cp ^ (row & 7)) << 4)) = h;
    }

    const int c0 = wave * 16;
    f16x8 bfrag[8];
    #pragma unroll
    for (int kt = 0; kt < 8; ++kt) {
        #pragma unroll
        for (int j = 0; j < 8; ++j) {
            int k = kt * 32 + kg * 8 + j;
            bfrag[kt][j] = (_Float16)Wc[k * 64 + c0 + colg];
        }
    }
    __syncthreads();

    f32x4 acc[4];
    #pragma unroll
    for (int mt = 0; mt < 4; ++mt) acc[mt] = (f32x4){0.f, 0.f, 0.f, 0.f};

    #pragma unroll
    for (int kt = 0; kt < 8; ++kt) {
        #pragma unroll
        for (int mt = 0; mt < 4; ++mt) {
            const int arow = mt * 16 + colg;
            const int chunk = kt * 4 + kg;
            f16x8 a = *reinterpret_cast<const f16x8*>(
                xbase + arow * 512 + ((chunk ^ (arow & 7)) << 4));
            acc[mt] = __builtin_amdgcn_mfma_f32_16x16x32_f16(a, bfrag[kt], acc[mt], 0, 0, 0);
        }
    }

    const int col  = c0 + colg;
    const float bias = bc[col];
    const int ph = col >> 3, pw = col & 7;
    #pragma unroll
    for (int mt = 0; mt < 4; ++mt) {
        #pragma unroll
        for (int r = 0; r < 4; ++r) {
            int tg = t0 + mt * 16 + kg * 4 + r;
            int hc = tg >> 5, wc = tg & 31;
            coarse_img[(size_t)b * 65536 + (hc * 8 + ph) * 256 + wc * 8 + pw]
                = acc[mt][r] + bias;
        }
    }
}

// ---------------- K2: sparse fine gather-GEMM over needed-j grid ----------------
__global__ __launch_bounds__(256) void k_mm2(const float* __restrict__ tokens,
                                             const float* __restrict__ Wf,
                                             const float* __restrict__ bf,
                                             const int* __restrict__ mask,
                                             const int* __restrict__ cum,
                                             float* __restrict__ patch_j,
                                             SampArgs sa) {
    __shared__ _Float16 Xs[64 * 256];          // 32 KB
    __shared__ int rowsrc[64];
    const int tid  = threadIdx.x;
    const int lane = tid & 63;
    const int wave = tid >> 6;
    char* xbase = reinterpret_cast<char*>(Xs);
    const int colg = lane & 15;
    const int kg   = lane >> 4;

    const int u0blk = blockIdx.x;
    const int b  = u0blk / sa.jblocks;
    const int u0 = (u0blk - b * sa.jblocks) * 64;

    if (tid < 64) {
        int u = u0 + tid;
        int ridx = -1;
        if (u < sa.nj) {
            int uh = u / sa.nhf;
            int uw = u - uh * sa.nhf;
            int j  = sa.hfl[uh] * 64 + sa.hfl[uw];
            if (mask[b * NF + j] != 0) ridx = cum[b * NF + j] - 1;
        }
        rowsrc[tid] = ridx;
    }
    __syncthreads();

    const int rgrp   = tid >> 6;
    const int lane64 = tid & 63;
    for (int it = 0; it < 16; ++it) {
        int rl = it * 4 + rgrp;
        int ridx = rowsrc[rl];
        int cp   = lane64 >> 1;
        int half = lane64 & 1;
        f16x4 hv = {0, 0, 0, 0};
        if (ridx >= 0) {
            const float* s = tokens + ((size_t)b * TOKSTRIDE + NC + ridx) * EE + lane64 * 4;
            float4 v = *reinterpret_cast<const float4*>(s);
            hv[0] = (_Float16)v.x; hv[1] = (_Float16)v.y;
            hv[2] = (_Float16)v.z; hv[3] = (_Float16)v.w;
        }
        *reinterpret_cast<f16x4*>(xbase + rl * 512 + (((cp ^ (rl & 7)) << 4) | (half << 3))) = hv;
    }

    f16x8 bfrag[8];
    #pragma unroll
    for (int kt = 0; kt < 8; ++kt) {
        #pragma unroll
        for (int j = 0; j < 8; ++j) {
            int k = kt * 32 + kg * 8 + j;
            bfrag[kt][j] = (_Float16)Wf[k * 16 + colg];
        }
    }
    __syncthreads();

    const int arow = wave * 16 + colg;
    const char* xrow = xbase + arow * 512;
    const int swz = arow & 7;
    f32x4 acc = {0.f, 0.f, 0.f, 0.f};
    #pragma unroll
    for (int kt = 0; kt < 8; ++kt) {
        const int chunk = kt * 4 + kg;
        f16x8 a = *reinterpret_cast<const f16x8*>(xrow + ((chunk ^ swz) << 4));
        acc = __builtin_amdgcn_mfma_f32_16x16x32_f16(a, bfrag[kt], acc, 0, 0, 0);
    }

    const float bias = bf[colg];
    #pragma unroll
    for (int r = 0; r < 4; ++r) {
        int ol = wave * 16 + kg * 4 + r;
        int u  = u0 + ol;
        if (u < sa.nj) {
            float v = (rowsrc[ol] >= 0) ? (acc[r] + bias) : 0.f;
            patch_j[((size_t)b * sa.nj + u) * 16 + colg] = v;
        }
    }
}

// ---------------- K3: fused conv + blend + downsample (4 lanes/pixel) ----------------
__global__ __launch_bounds__(256) void k_out(const float* __restrict__ coarse_img,
                                             const float* __restrict__ patch_j,
                                             const float* __restrict__ noise,
                                             const float* __restrict__ convw,
                                             float* __restrict__ out,
                                             SampArgs sa) {
    const int gt = blockIdx.x * 256 + threadIdx.x;    // 131072 threads
    const int o  = gt >> 2;                           // output index 0..32767
    const int corner = gt & 3;
    const int a = corner >> 1, c = corner & 1;

    const int b = o >> 10;
    const int p = (o >> 5) & 31;
    const int q = o & 31;

    float kk[9];
    #pragma unroll
    for (int i = 0; i < 9; ++i) kk[i] = convw[i];

    const int   h  = a ? sa.i1[p] : sa.i0[p];
    const int   w  = c ? sa.i1[q] : sa.i0[q];
    const float fh = sa.fr[p], fw = sa.fr[q];
    const float wt = (a ? fh : 1.f - fh) * (c ? fw : 1.f - fw);

    const float* cimg = coarse_img + (size_t)b*65536;
    const float* nimg = noise      + (size_t)b*65536;

    float conv = 0.f;
    #pragma unroll
    for (int dh = -1; dh <= 1; ++dh) {
        #pragma unroll
        for (int dw = -1; dw <= 1; ++dw) {
            int hh = h + dh, wp = w + dw;
            float v = (hh >= 0 && hh < IMG && wp >= 0 && wp < IMG)
                      ? cimg[hh*IMG + wp] : 0.f;
            conv = fmaf(v, kk[(dh+1)*3 + (dw+1)], conv);
        }
    }
    const int jj = sa.inv[h >> 2] * sa.nhf + sa.inv[w >> 2];
    const int colx = (h & 3) * 4 + (w & 3);
    float fv = patch_j[((size_t)b * sa.nj + jj) * 16 + colx];

    float s = 1.f / (1.f + expf(-0.1f * nimg[h*IMG + w]));
    float val = wt * (conv * (1.f - s) + fv * s);

    val += __shfl_xor(val, 1, 64);
    val += __shfl_xor(val, 2, 64);
    if (corner == 0) out[o] = val;
}

extern "C" void kernel_launch(void* const* d_in, const int* in_sizes, int n_in,
                              void* d_out, int out_size, void* d_ws, size_t ws_size,
                              hipStream_t stream) {
    const float* tokens = (const float*)d_in[0];
    const int*   mask   = (const int*)  d_in[1];
    const float* Wc     = (const float*)d_in[2];
    const float* bc     = (const float*)d_in[3];
    const float* Wf     = (const float*)d_in[4];
    const float* bf     = (const float*)d_in[5];
    const float* convw  = (const float*)d_in[6];
    const float* noise  = (const float*)d_in[7];

    // interp + needed-hf structures (host, deterministic)
    SampArgs sa;
    bool need[64] = {false};
    for (int p = 0; p < 32; ++p) {
        double pos = (double)p * 255.0 / 31.0;
        int i0 = (int)floor(pos);
        int i1 = (i0 + 1 < 256) ? i0 + 1 : 255;
        sa.i0[p] = i0; sa.i1[p] = i1; sa.fr[p] = (float)(pos - (double)i0);
        need[i0 >> 2] = true; need[i1 >> 2] = true;
    }
    int nhf = 0;
    for (int hf = 0; hf < 64; ++hf) {
        sa.inv[hf] = 0;
        if (need[hf]) { sa.inv[hf] = nhf; sa.hfl[nhf++] = hf; }
    }
    for (int i = nhf; i < MAXHF; ++i) sa.hfl[i] = 0;
    sa.nhf = nhf;
    sa.nj  = nhf * nhf;
    sa.jblocks = (sa.nj + 63) / 64;

    float* ws = (float*)d_ws;
    float* coarse_img = ws;                               // 32*65536 floats
    float* patch_j    = ws + (size_t)BB*65536;            // 32*nj*16 floats
    int*   cum        = (int*)(ws + (size_t)2*BB*65536);  // 32*4096 ints

    k_mm1<<<544, 256, 0, stream>>>(tokens, Wc, bc, mask, cum, coarse_img);
    k_mm2<<<BB * sa.jblocks, 256, 0, stream>>>(tokens, Wf, bf, mask, cum,
                                               patch_j, sa);
    k_out<<<512, 256, 0, stream>>>(coarse_img, patch_j, noise, convw,
                                   (float*)d_out, sa);
}